// Round 1
// baseline (243.927 us; speedup 1.0000x reference)
//
#include <hip/hip_runtime.h>

// Soft decision tree, DEPTH=8: 255 internal nodes (heap order = BFS level order),
// 256 leaves, 10 classes, B=131072, 32 features.
// One thread per batch element. Per-thread feature row lives in LDS (pad 33 ->
// bank-conflict-free uniform-index gather). Per-thread class accumulators in LDS
// (pad 11, ds_add_f32 via atomicAdd on own slots -> 1 LDS op per leaf).
// Tree walked by fully-inlined template DFS; split at depth 4 (mid path-probs
// staged in LDS, pad 17) to keep code size ~4KB. exp(-(x-t)) computed as
// exp2(t*log2e - x*log2e) with log2e folded into the staged params.

#define TDEPTH   8
#define NFEAT    32
#define NCLS     10
#define TPB      256
#define XPAD     33
#define APAD     11
#define PMPAD    17
#define SPLIT    4
#define MIDBASE  15    // 2^4 - 1
#define LEAFBASE 255   // 2^8 - 1
#define L2E      1.4426950408889634f

__device__ __forceinline__ float fexp2(float z) {
#if __has_builtin(__builtin_amdgcn_exp2f)
  return __builtin_amdgcn_exp2f(z);   // raw v_exp_f32
#else
  return exp2f(z);
#endif
}

__device__ __forceinline__ float frcp(float z) {
#if __has_builtin(__builtin_amdgcn_rcpf)
  return __builtin_amdgcn_rcpf(z);    // raw v_rcp_f32
#else
  return 1.0f / z;
#endif
}

// act = sigmoid(x - t) = 1/(1+e), e = exp(t - x) = exp2(t2 - x2)
// 1 - act = e * act
__device__ __forceinline__ void node_factors(int node, int tid,
    const float* s_thr, const int* s_feat, const float* s_x,
    float p, float& pl, float& pr) {
  const int   f  = s_feat[node];            // LDS broadcast (uniform)
  const float t2 = s_thr[node];             // LDS broadcast (uniform)
  const float x2 = s_x[tid * XPAD + f];     // conflict-free gather
  const float e  = fexp2(t2 - x2);
  const float a  = frcp(1.0f + e);
  pr = p * a;        // right child: p * act
  pl = pr * e;       // left  child: p * (1-act) = p * act * e
}

template <int D>
__device__ __forceinline__ void dfs_top(int node, float p, int tid,
    const float* s_thr, const int* s_feat, const float* s_x, float* s_pm) {
  if constexpr (D == SPLIT) {
    s_pm[tid * PMPAD + (node - MIDBASE)] = p;   // own slot, no barrier needed
  } else {
    float pl, pr;
    node_factors(node, tid, s_thr, s_feat, s_x, p, pl, pr);
    dfs_top<D + 1>(2 * node + 1, pl, tid, s_thr, s_feat, s_x, s_pm);
    dfs_top<D + 1>(2 * node + 2, pr, tid, s_thr, s_feat, s_x, s_pm);
  }
}

template <int D>
__device__ __forceinline__ void dfs_bot(int node, float p, int tid,
    const float* s_thr, const int* s_feat, const float* s_x,
    const int* __restrict__ g_leafc, float* s_acc) {
  if constexpr (D == TDEPTH) {
    const int lc = g_leafc[node - LEAFBASE];        // uniform -> s_load (K$)
    atomicAdd(&s_acc[tid * APAD + lc], p);          // ds_add_f32, own slot
  } else {
    float pl, pr;
    node_factors(node, tid, s_thr, s_feat, s_x, p, pl, pr);
    dfs_bot<D + 1>(2 * node + 1, pl, tid, s_thr, s_feat, s_x, g_leafc, s_acc);
    dfs_bot<D + 1>(2 * node + 2, pr, tid, s_thr, s_feat, s_x, g_leafc, s_acc);
  }
}

__global__ __launch_bounds__(TPB, 2)
void dt_kernel(const float* __restrict__ x,
               const float* __restrict__ thresholds,
               const int*   __restrict__ feats,
               const int*   __restrict__ leaf_class,
               float*       __restrict__ out,
               int B) {
  __shared__ float s_thr[256];          // thresholds * log2e
  __shared__ int   s_feat[256];
  __shared__ float s_x[TPB * XPAD];     // x * log2e, pad 33
  __shared__ float s_pm[TPB * PMPAD];   // depth-4 path probs, pad 17
  __shared__ float s_acc[TPB * APAD];   // class accumulators, pad 11
  // total LDS = 1024 + 1024 + 33792 + 17408 + 11264 = 64512 B -> 2 blocks/CU

  const int tid = threadIdx.x;

  // --- stage tree params (scaled) ---
  if (tid < 255) {
    s_thr[tid]  = thresholds[tid] * L2E;
    s_feat[tid] = feats[tid];
  }

  // --- stage x, coalesced float4, scaled by log2e ---
  const float4* xg = (const float4*)x;
  const int b4 = blockIdx.x * (TPB * NFEAT / 4);
  const int lim4 = B * (NFEAT / 4);
#pragma unroll
  for (int k = 0; k < 8; ++k) {
    const int i4 = k * TPB + tid;           // 0..2047
    if (b4 + i4 < lim4) {
      float4 v = xg[b4 + i4];
      const int row = i4 >> 3;              // local batch row
      const int c4  = i4 & 7;
      float* d = &s_x[row * XPAD + c4 * 4];
      d[0] = v.x * L2E; d[1] = v.y * L2E; d[2] = v.z * L2E; d[3] = v.w * L2E;
    }
  }

  // --- zero own class accumulators ---
#pragma unroll
  for (int c = 0; c < NCLS; ++c) s_acc[tid * APAD + c] = 0.0f;

  __syncthreads();

  // --- depths 0..3: 15 sigmoids -> 16 mid path-probs ---
  dfs_top<0>(0, 1.0f, tid, s_thr, s_feat, s_x, s_pm);
  // own slots only -> no barrier

  // --- depths 4..7 per subtree: 15 sigmoids + 16 leaf accumulates ---
#pragma unroll 1
  for (int s = 0; s < 16; ++s) {
    const float p = s_pm[tid * PMPAD + s];
    dfs_bot<SPLIT>(MIDBASE + s, p, tid, s_thr, s_feat, s_x, leaf_class, s_acc);
  }

  __syncthreads();   // drain ds_adds; cross-thread reads below

  // --- transposed, fully-coalesced output write ---
  const unsigned blockOutBase = (unsigned)blockIdx.x * (TPB * NCLS);
  const unsigned total = (unsigned)B * NCLS;
#pragma unroll
  for (int k = 0; k < NCLS; ++k) {
    const unsigned j = (unsigned)k * TPB + tid;    // 0..2559
    const unsigned g = blockOutBase + j;
    if (g < total) {
      const unsigned row = j / NCLS;               // magic-mul div by 10
      const unsigned c   = j - row * NCLS;
      out[g] = s_acc[row * APAD + c];
    }
  }
}

extern "C" void kernel_launch(void* const* d_in, const int* in_sizes, int n_in,
                              void* d_out, int out_size, void* d_ws, size_t ws_size,
                              hipStream_t stream) {
  const float* x          = (const float*)d_in[0];
  const float* thresholds = (const float*)d_in[1];
  const int*   feats      = (const int*)d_in[2];
  const int*   leaf_class = (const int*)d_in[3];
  float*       out        = (float*)d_out;

  const int B = in_sizes[0] / NFEAT;          // 131072
  const int grid = (B + TPB - 1) / TPB;       // 512

  dt_kernel<<<grid, TPB, 0, stream>>>(x, thresholds, feats, leaf_class, out, B);
}

// Round 2
// 242.272 us; speedup vs baseline: 1.0068x; 1.0068x over previous
//
#include <hip/hip_runtime.h>

// Soft decision tree DEPTH=8, 255 internal nodes (heap order), 256 leaves,
// 10 classes, B=131072, 32 feats. fp32 in/out.
//
// Round-2 design (fixing R1's latency serialization, 183us @ 5% VALUBusy):
//  - TWO threads per row: thread t handles half h=t>>7 of the tree
//    (4 of 8 depth-3 subtrees). 4096 waves -> 4 waves/SIMD resident.
//  - PURE-DS hot loop: no SMEM (s_load) mixing with ds_read on lgkmcnt.
//    Node params packed in LDS: depth 0..6 -> int2{t*log2e, feat} (ds_read_b64
//    broadcast), depth 7 -> int4{t*log2e, feat, leaf_class_L, leaf_class_R}
//    (ds_read_b128 broadcast). 2 DS ops per sigmoid total.
//  - s_x TRANSPOSED: x[f*128+row], f wave-uniform -> uniform-base + lane-linear
//    ds_read_b32, conflict-free, no padding. Pre-scaled by log2e.
//  - Mid (depth-3) path probs live in 4 registers; no LDS staging for them.
//  - Class accumulation: ds_add_f32 (atomicAdd on own row slot, fire-and-forget),
//    s_acc[c*128+row] lane-linear -> conflict-free.
// LDS/block = 1016 + 2048 + 16384 + 5120 = 24568 B.

#define NFEAT 32
#define NCLS  10
#define TPB   256
#define RPB   128          // rows per block (2 threads per row)
#define L2E   1.4426950408889634f

__device__ __forceinline__ float fexp2(float z) {
#if __has_builtin(__builtin_amdgcn_exp2f)
  return __builtin_amdgcn_exp2f(z);   // raw v_exp_f32
#else
  return exp2f(z);
#endif
}
__device__ __forceinline__ float frcp(float z) {
#if __has_builtin(__builtin_amdgcn_rcpf)
  return __builtin_amdgcn_rcpf(z);    // raw v_rcp_f32
#else
  return 1.0f / z;
#endif
}

struct SH {
  int2  nd[127];           // depths 0..6: {float t2 bits, feat}
  int4  nd7[128];          // depth 7: {float t2 bits, feat, lcL, lcR}
  float x[NFEAT * RPB];    // transposed, pre-scaled by log2e
  float acc[NCLS * RPB];   // class accumulators, c-major
};

// sigmoid(x-t): e = exp2(t2 - x2); act = 1/(1+e); 1-act = e*act
__device__ __forceinline__ void evaln(const SH& sh, int n, int row, float p,
                                      float& pl, float& pr) {
  const int2 r = sh.nd[n];                     // ds_read_b64, broadcast
  const float x2 = sh.x[(r.y << 7) + row];     // ds_read_b32, lane-linear
  const float e = fexp2(__int_as_float(r.x) - x2);
  const float a = frcp(1.0f + e);
  pr = p * a;
  pl = pr * e;
}

template <int D>
__device__ __forceinline__ void dfs(SH& sh, int n, int row, float p) {
  if constexpr (D == 7) {
    const int4 r = sh.nd7[n - 127];            // ds_read_b128, broadcast
    const float x2 = sh.x[(r.y << 7) + row];
    const float e = fexp2(__int_as_float(r.x) - x2);
    const float a = frcp(1.0f + e);
    const float pr = p * a;
    const float pl = pr * e;
    atomicAdd(&sh.acc[(r.z << 7) + row], pl);  // ds_add_f32, no return
    atomicAdd(&sh.acc[(r.w << 7) + row], pr);
  } else {
    float pl, pr;
    evaln(sh, n, row, p, pl, pr);
    dfs<D + 1>(sh, 2 * n + 1, row, pl);
    dfs<D + 1>(sh, 2 * n + 2, row, pr);
  }
}

__global__ __launch_bounds__(TPB, 4)
void dt_kernel(const float* __restrict__ x,
               const float* __restrict__ thr,
               const int*   __restrict__ feats,
               const int*   __restrict__ leafc,
               float*       __restrict__ out) {
  __shared__ SH sh;
  const int t   = threadIdx.x;
  const int row = t & (RPB - 1);
  const int h   = t >> 7;                      // wave-uniform half select

  // --- stage node params (once) ---
  if (t < 127) {
    sh.nd[t] = make_int2(__float_as_int(thr[t] * L2E), feats[t]);
  } else if (t < 255) {
    const int n7 = t - 127;
    sh.nd7[n7] = make_int4(__float_as_int(thr[t] * L2E), feats[t],
                           leafc[2 * n7], leafc[2 * n7 + 1]);
  }

  // --- stage x: coalesced float4 reads, transposed conflict-lite LDS writes ---
  const float4* xg = (const float4*)x + (size_t)blockIdx.x * (RPB * NFEAT / 4);
#pragma unroll
  for (int k = 0; k < 4; ++k) {
    const int i4 = k * TPB + t;                // 0..1023
    const float4 v = xg[i4];
    const int r  = i4 >> 3;                    // local row
    const int c0 = (i4 & 7) * 4;               // first of 4 feature columns
    sh.x[(c0 + 0) * RPB + r] = v.x * L2E;
    sh.x[(c0 + 1) * RPB + r] = v.y * L2E;
    sh.x[(c0 + 2) * RPB + r] = v.z * L2E;
    sh.x[(c0 + 3) * RPB + r] = v.w * L2E;
  }

  // --- zero accumulators ---
#pragma unroll
  for (int k = 0; k < 5; ++k) sh.acc[k * TPB + t] = 0.0f;

  __syncthreads();

  // --- top of tree: 4 sigmoids give this thread's 4 depth-3 probs ---
  float pl, pr;
  evaln(sh, 0, row, 1.0f, pl, pr);
  const float pd1 = h ? pr : pl;               // prob of node 1+h
  evaln(sh, 1 + h, row, pd1, pl, pr);
  const float pA = pl, pB = pr;                // probs of nodes 3+2h, 4+2h
  float pm0, pm1, pm2, pm3;
  evaln(sh, 3 + 2 * h, row, pA, pm0, pm1);     // -> nodes 7+4h, 8+4h
  evaln(sh, 4 + 2 * h, row, pB, pm2, pm3);     // -> nodes 9+4h, 10+4h

  // --- 4 depth-3..7 subtrees (15 b64-evals + 16 b128 leaf-pairs each) ---
  const int mb = 7 + 4 * h;
#pragma unroll 1
  for (int s = 0; s < 4; ++s) {
    const float p = (s == 0) ? pm0 : (s == 1) ? pm1 : (s == 2) ? pm2 : pm3;
    dfs<3>(sh, mb + s, row, p);
  }

  __syncthreads();                              // drain ds_adds

  // --- coalesced output write ---
  float* og = out + (size_t)blockIdx.x * (RPB * NCLS);
#pragma unroll
  for (int k = 0; k < 5; ++k) {
    const int j = k * TPB + t;                 // 0..1279
    const int r = j / NCLS;                    // magic-mul
    const int c = j - r * NCLS;
    og[j] = sh.acc[(c << 7) + r];
  }
}

extern "C" void kernel_launch(void* const* d_in, const int* in_sizes, int n_in,
                              void* d_out, int out_size, void* d_ws, size_t ws_size,
                              hipStream_t stream) {
  const float* x     = (const float*)d_in[0];
  const float* thr   = (const float*)d_in[1];
  const int*   feats = (const int*)d_in[2];
  const int*   leafc = (const int*)d_in[3];
  float*       out   = (float*)d_out;

  const int B    = in_sizes[0] / NFEAT;        // 131072
  const int grid = B / RPB;                    // 1024

  dt_kernel<<<grid, TPB, 0, stream>>>(x, thr, feats, leafc, out);
}

// Round 4
// 85.861 us; speedup vs baseline: 2.8409x; 2.8217x over previous
//
#include <hip/hip_runtime.h>

// Soft decision tree DEPTH=8, 255 internal nodes (heap order), 256 leaves,
// 10 classes, B=131072, 32 feats. fp32 in/out.
//
// R4 = R3 with the race fixed: accumulators indexed by THREAD (t, stride 256
// per class), not by row — with 2 threads/row, t and t+128 shared row slots,
// which is why R2 needed atomicAdd and why R3 (plain RMW on row slots) was
// wrong by a path-prob. Now slots are truly thread-private:
//   - plain LDS RMW (ds_read + v_add + ds_write), no atomics,
//   - TWO copies (L-leaves -> accA, R-leaves -> accB): two independent
//     in-order DS chains, interleaved,
//   - epilogue merges A/B and both halves (4 reads per output).
// Unchanged from R2: 2 threads/row (4096 waves), pure-DS hot loop, packed
// node records (b64 depths 0..6 / b128 depth 7 incl. leaf classes),
// transposed conflict-free s_xT pre-scaled by log2e, depth-3 probs in regs.
// LDS/block = 1016 + 2048 + 16384 + 2*10240 = 39928 B -> 4 blocks/CU.

#define NFEAT 32
#define NCLS  10
#define TPB   256
#define RPB   128          // rows per block (2 threads per row)
#define L2E   1.4426950408889634f

__device__ __forceinline__ float fexp2(float z) {
#if __has_builtin(__builtin_amdgcn_exp2f)
  return __builtin_amdgcn_exp2f(z);   // raw v_exp_f32
#else
  return exp2f(z);
#endif
}
__device__ __forceinline__ float frcp(float z) {
#if __has_builtin(__builtin_amdgcn_rcpf)
  return __builtin_amdgcn_rcpf(z);    // raw v_rcp_f32
#else
  return 1.0f / z;
#endif
}

// sigmoid(x-t): e = exp2(t2 - x2); act = 1/(1+e); 1-act = e*act
__device__ __forceinline__ void evaln(const int2* nd, const float* xT,
                                      int n, int row, float p,
                                      float& pl, float& pr) {
  const int2 r = nd[n];                        // ds_read_b64, broadcast (addr compile-time)
  const float x2 = xT[(r.y << 7) + row];       // ds_read_b32, lane-linear
  const float e = fexp2(__int_as_float(r.x) - x2);
  const float a = frcp(1.0f + e);
  pr = p * a;
  pl = pr * e;
}

template <int D>
__device__ __forceinline__ void dfs(const int2* nd, const int4* nd7,
                                    const float* xT, float* accA, float* accB,
                                    int n, int t, int row, float p) {
  if constexpr (D == 7) {
    const int4 r = nd7[n - 127];               // ds_read_b128, broadcast
    const float x2 = xT[(r.y << 7) + row];
    const float e = fexp2(__int_as_float(r.x) - x2);
    const float a = frcp(1.0f + e);
    const float pr = p * a;
    const float pl = pr * e;
    accA[(r.z << 8) + t] += pl;                // plain RMW, THREAD-private slot
    accB[(r.w << 8) + t] += pr;                // separate array: independent chain
  } else {
    float pl, pr;
    evaln(nd, xT, n, row, p, pl, pr);
    dfs<D + 1>(nd, nd7, xT, accA, accB, 2 * n + 1, t, row, pl);
    dfs<D + 1>(nd, nd7, xT, accA, accB, 2 * n + 2, t, row, pr);
  }
}

__global__ __launch_bounds__(TPB, 4)
void dt_kernel(const float* __restrict__ x,
               const float* __restrict__ thr,
               const int*   __restrict__ feats,
               const int*   __restrict__ leafc,
               float*       __restrict__ out) {
  __shared__ int2  s_nd[127];          // depths 0..6: {t*log2e bits, feat}
  __shared__ int4  s_nd7[128];         // depth 7: {t*log2e bits, feat, lcL, lcR}
  __shared__ float s_xT[NFEAT * RPB];  // transposed, pre-scaled by log2e
  __shared__ float s_accA[NCLS * TPB]; // per-THREAD class accumulators (L leaves)
  __shared__ float s_accB[NCLS * TPB]; // per-THREAD class accumulators (R leaves)

  const int t   = threadIdx.x;
  const int row = t & (RPB - 1);
  const int h   = t >> 7;              // wave-uniform half select

  // --- stage node params (once) ---
  if (t < 127) {
    s_nd[t] = make_int2(__float_as_int(thr[t] * L2E), feats[t]);
  } else if (t < 255) {
    const int n7 = t - 127;
    s_nd7[n7] = make_int4(__float_as_int(thr[t] * L2E), feats[t],
                          leafc[2 * n7], leafc[2 * n7 + 1]);
  }

  // --- stage x: coalesced float4 reads, transposed LDS writes ---
  const float4* xg = (const float4*)x + (size_t)blockIdx.x * (RPB * NFEAT / 4);
#pragma unroll
  for (int k = 0; k < 4; ++k) {
    const int i4 = k * TPB + t;                // 0..1023
    const float4 v = xg[i4];
    const int r  = i4 >> 3;                    // local row
    const int c0 = (i4 & 7) * 4;               // first of 4 feature columns
    s_xT[(c0 + 0) * RPB + r] = v.x * L2E;
    s_xT[(c0 + 1) * RPB + r] = v.y * L2E;
    s_xT[(c0 + 2) * RPB + r] = v.z * L2E;
    s_xT[(c0 + 3) * RPB + r] = v.w * L2E;
  }

  // --- zero accumulators ---
#pragma unroll
  for (int k = 0; k < NCLS; ++k) {
    s_accA[k * TPB + t] = 0.0f;
    s_accB[k * TPB + t] = 0.0f;
  }

  __syncthreads();

  // --- top of tree: 4 sigmoids give this thread's 4 depth-3 probs ---
  float pl, pr;
  evaln(s_nd, s_xT, 0, row, 1.0f, pl, pr);
  const float pd1 = h ? pr : pl;               // prob of node 1+h
  evaln(s_nd, s_xT, 1 + h, row, pd1, pl, pr);
  const float pA = pl, pB = pr;                // probs of nodes 3+2h, 4+2h
  float pm0, pm1, pm2, pm3;
  evaln(s_nd, s_xT, 3 + 2 * h, row, pA, pm0, pm1);
  evaln(s_nd, s_xT, 4 + 2 * h, row, pB, pm2, pm3);

  // --- 4 depth-3..7 subtrees ---
  const int mb = 7 + 4 * h;
#pragma unroll 1
  for (int s = 0; s < 4; ++s) {
    const float p = (s == 0) ? pm0 : (s == 1) ? pm1 : (s == 2) ? pm2 : pm3;
    dfs<3>(s_nd, s_nd7, s_xT, s_accA, s_accB, mb + s, t, row, p);
  }

  __syncthreads();                             // cross-thread reads below

  // --- coalesced output write: merge A/B copies and both tree halves ---
  float* og = out + (size_t)blockIdx.x * (RPB * NCLS);
#pragma unroll
  for (int k = 0; k < 5; ++k) {
    const int j = k * TPB + t;                 // 0..1279
    const int r = j / NCLS;                    // magic-mul
    const int c = j - r * NCLS;
    og[j] = (s_accA[(c << 8) + r] + s_accA[(c << 8) + RPB + r]) +
            (s_accB[(c << 8) + r] + s_accB[(c << 8) + RPB + r]);
  }
}

extern "C" void kernel_launch(void* const* d_in, const int* in_sizes, int n_in,
                              void* d_out, int out_size, void* d_ws, size_t ws_size,
                              hipStream_t stream) {
  const float* x     = (const float*)d_in[0];
  const float* thr   = (const float*)d_in[1];
  const int*   feats = (const int*)d_in[2];
  const int*   leafc = (const int*)d_in[3];
  float*       out   = (float*)d_out;

  const int B    = in_sizes[0] / NFEAT;        // 131072
  const int grid = B / RPB;                    // 1024

  dt_kernel<<<grid, TPB, 0, stream>>>(x, thr, feats, leafc, out);
}